// Round 9
// baseline (2654.364 us; speedup 1.0000x reference)
//
#include <hip/hip_runtime.h>
#include <hip/hip_bf16.h>

#define T_LEN 2048
#define BATCH 32
#define HDIM 256
#define H3 768
#define EMBD 63
#define NSING 1024

typedef _Float16 half8 __attribute__((ext_vector_type(8)));
typedef _Float16 half4 __attribute__((ext_vector_type(4)));
typedef float f32x4 __attribute__((ext_vector_type(4)));
typedef unsigned u32x4 __attribute__((ext_vector_type(4)));

#define DPP_ADD(x, ctrl)                                                      \
  (x) += __builtin_bit_cast(                                                  \
      float, __builtin_amdgcn_update_dpp(                                     \
                 0, __builtin_bit_cast(int, (x)), (ctrl), 0xf, 0xf, true))

// P4[(s*256 + c)*4 + {0,1,2}] = (p_r, p_z, p_n) f16 for one direction.
__global__ __launch_bounds__(256) void precompute_P(
    const float* __restrict__ embed, const float* __restrict__ Wi,
    const float* __restrict__ bi, _Float16* __restrict__ P4) {
  const int s = blockIdx.x;
  const int c = threadIdx.x;
  float ar = bi[c], az = bi[HDIM + c], an = bi[2 * HDIM + c];
  const float* er = embed + s * EMBD;
#pragma unroll
  for (int e = 0; e < EMBD; e++) {
    const float ev = er[e];
    ar += ev * Wi[(e + 1) * H3 + c];
    az += ev * Wi[(e + 1) * H3 + HDIM + c];
    an += ev * Wi[(e + 1) * H3 + 2 * HDIM + c];
  }
  half4 h = {(_Float16)ar, (_Float16)az, (_Float16)an, (_Float16)0.f};
  *(half4*)(P4 + ((size_t)s * HDIM + c) * 4) = h;
}

// B-fragment pack, verified LAYOUT_II k-mapping (rounds 6-8 absmax pass).
// bid = ((dir*4 + w)*12 + idx)*8 + kt ; idx = gate*4 + i ; nt = gate*16+w*4+i
__global__ __launch_bounds__(64) void pack_B(
    const float* __restrict__ Wh_f, const float* __restrict__ Wh_b,
    uint4* __restrict__ Bp) {
  const int bid = blockIdx.x;
  const int kt = bid & 7;
  const int idx = (bid >> 3) % 12;
  const int w = (bid / 96) & 3;
  const int d = bid / 384;
  const int l = threadIdx.x;
  const int g = l >> 4;
  const int gate = idx >> 2, i = idx & 3;
  const int nt = gate * 16 + w * 4 + i;
  const int j = nt * 16 + (l & 15);
  const float* Wh = d ? Wh_b : Wh_f;
  unsigned int dw[4];
#pragma unroll
  for (int r = 0; r < 4; r++) {
    const int k = kt * 32 + (r >= 2 ? 16 : 0) + g * 4 + (r & 1) * 2;
    _Float16 lo = (_Float16)Wh[k * H3 + j];
    _Float16 hi = (_Float16)Wh[(k + 1) * H3 + j];
    dw[r] = (unsigned int)__builtin_bit_cast(unsigned short, lo) |
            ((unsigned int)__builtin_bit_cast(unsigned short, hi) << 16);
  }
  Bp[(size_t)bid * 64 + l] = make_uint4(dw[0], dw[1], dw[2], dw[3]);
}

// One block per (dir,b): 256 threads = 4 waves = 1 wave/SIMD (512 unified
// regs). Wave w owns cols [64w,64w+64): 12 N-tiles x 8 kt = 96 B-frags =
// 384 dwords/lane. Rounds 1-8 post-mortem: intrinsic MFMA always copies
// AGPR-homed operands through VGPRs (v_accvgpr_read per use). Fix: inline
// asm v_mfma with explicit "a" constraints -- srcB reads AGPRs NATIVELY
// (ISA sec 10). AGPR arch cap is 256, so split: frags 0-47 -> AGPR (192) +
// acc 48 AGPR = 240; frags 48-95 -> arch VGPR (192) + ~40 locals = ~232.
__global__ __attribute__((amdgpu_flat_work_group_size(256, 256),
                          amdgpu_waves_per_eu(1, 1))) void gru_scan(
    const float* __restrict__ dur, const int* __restrict__ sid,
    const uint4* __restrict__ Bp,
    const float* __restrict__ Wi_f, const float* __restrict__ Wi_b,
    const float* __restrict__ bhn_f, const float* __restrict__ bhn_b,
    const float* __restrict__ Wd, const float* __restrict__ bd,
    const _Float16* __restrict__ P4,  // [dir][s][256][4] f16
    float* __restrict__ out) {        // [B][T] f32, pre-zeroed, atomicAdd
  const int b = blockIdx.x & 31;
  const int dir = blockIdx.x >> 5;
  const int tid = threadIdx.x;
  const int l = tid & 63;
  const int w = tid >> 6;
  const int g = l >> 4;      // A-fragment lane group == my N-sub-tile index
  const int c = w * 64 + l;  // my gate/output column (0..255)

  __shared__ __align__(16) _Float16 hp[2][HDIM];  // permuted-h, double-buf

  // ---- B fragments: 48 AGPR-homed + 48 VGPR-homed (homes forced by the
  // asm operand constraints at every use; no copies) ----
  u32x4 bfrA[48], bfrV[48];
  {
    const u32x4* bp = (const u32x4*)(Bp + ((size_t)(dir * 4 + w) * 96) * 64 + l);
#pragma unroll
    for (int f = 0; f < 48; f++) bfrA[f] = bp[f * 64];
#pragma unroll
    for (int f = 0; f < 48; f++) bfrV[f] = bp[(48 + f) * 64];
  }

  const float* __restrict__ Wi = dir ? Wi_b : Wi_f;
  const float wir = Wi[c], wiz = Wi[HDIM + c], win = Wi[2 * HDIM + c];
  const float bh = (dir ? bhn_b : bhn_f)[c];
  const float wd = Wd[dir * HDIM + c];
  const float bdv = bd[0];

  // permuted position of col c in the A-fragment k-order (verified r6-r8):
  const int pos = ((c >> 5) << 5) + (((c & 15) >> 2) << 3) +
                  (((c >> 4) & 1) << 2) + (c & 3);
  char* const hbase = (char*)&hp[0][0];
  unsigned rb = g * 16;         // read base byte (buf 0)
  unsigned wb = 512 + pos * 2;  // write base byte (buf 1)

  if (tid < 128) ((unsigned int*)hbase)[tid] = 0u;  // zero hp[0]
  float hprev = 0.f;

  const float* durb = dur + b * T_LEN;
  const int* sidb = sid + b * T_LEN;
  const _Float16* Pdir = P4 + (size_t)dir * NSING * HDIM * 4;
  float* outb = out + (size_t)b * T_LEN;

  int s_cur = sidb[dir ? (T_LEN - 1) : 0];
  float d_cur = durb[dir ? (T_LEN - 1) : 0];
  __syncthreads();

#pragma unroll 1
  for (int t = 0; t < T_LEN; t++) {
    const int tt = dir ? (T_LEN - 1 - t) : t;
    const int tn = (t + 1 < T_LEN) ? (t + 1) : t;
    const int ttn = dir ? (T_LEN - 1 - tn) : tn;

    // input-gate gather (consumed after MFMAs; latency hides under them)
    const half4 pv = *(const half4*)(Pdir + ((size_t)s_cur * HDIM + c) * 4);
    const int s_nx = sidb[ttn];
    const float d_nx = durb[ttn];

    f32x4 acc[12];
#pragma unroll
    for (int kt = 0; kt < 8; kt++) {
      const half8 a = *(const half8*)(hbase + rb + kt * 64);  // broadcast
#pragma unroll
      for (int q = 0; q < 12; q++) {
        if (kt == 0) {
          if (q < 6)
            asm("v_mfma_f32_16x16x32_f16 %0, %1, %2, 0"
                : "=a"(acc[q]) : "v"(a), "a"(bfrA[q * 8]));
          else
            asm("v_mfma_f32_16x16x32_f16 %0, %1, %2, 0"
                : "=a"(acc[q]) : "v"(a), "v"(bfrV[(q - 6) * 8]));
        } else {
          if (q < 6)
            asm("v_mfma_f32_16x16x32_f16 %0, %1, %2, %0"
                : "+a"(acc[q]) : "v"(a), "a"(bfrA[q * 8 + kt]));
          else
            asm("v_mfma_f32_16x16x32_f16 %0, %1, %2, %0"
                : "+a"(acc[q]) : "v"(a), "v"(bfrV[(q - 6) * 8 + kt]));
        }
      }
    }
    // hazard fence: >=24 cycles between last MFMA write and VALU acc reads;
    // "+a" operands data-order the subsequent v_accvgpr_read after this.
    asm volatile("s_nop 7\n\ts_nop 7\n\ts_nop 7"
                 : "+a"(acc[0]), "+a"(acc[1]), "+a"(acc[2]), "+a"(acc[3]),
                   "+a"(acc[4]), "+a"(acc[5]), "+a"(acc[6]), "+a"(acc[7]),
                   "+a"(acc[8]), "+a"(acc[9]), "+a"(acc[10]), "+a"(acc[11]));

    // all acc rows equal (broadcast A) -> reg 0 holds gh for col nt*16+(l&15)
    const float ghr = g == 0 ? acc[0][0] : g == 1 ? acc[1][0]
                     : g == 2 ? acc[2][0] : acc[3][0];
    const float ghz = g == 0 ? acc[4][0] : g == 1 ? acc[5][0]
                     : g == 2 ? acc[6][0] : acc[7][0];
    const float ghn = g == 0 ? acc[8][0] : g == 1 ? acc[9][0]
                     : g == 2 ? acc[10][0] : acc[11][0];

    const float xr = (float)pv[0] + d_cur * wir + ghr;
    const float xz = (float)pv[1] + d_cur * wiz + ghz;
    const float r = 1.f / (1.f + __expf(-xr));
    const float z = 1.f / (1.f + __expf(-xz));
    const float nin = (float)pv[2] + d_cur * win + r * (ghn + bh);
    const float n = 1.f - 2.f / (1.f + __expf(2.f * nin));  // tanh, safe
    const float h_new = n + z * (hprev - n);
    hprev = h_new;
    *(_Float16*)(hbase + wb) = (_Float16)h_new;

    // fused output head: full-wave DPP reduce, one atomic per wave
    float pd = h_new * wd;
    DPP_ADD(pd, 0x111);
    DPP_ADD(pd, 0x112);
    DPP_ADD(pd, 0x114);
    DPP_ADD(pd, 0x118);
    DPP_ADD(pd, 0x142);
    DPP_ADD(pd, 0x143);  // lane63 = wave total over its 64 cols
    if (l == 63) {
      float v = pd;
      if (dir == 0 && w == 0) v += bdv;  // bias added exactly once per elem
      unsafeAtomicAdd(outb + tt, v);
    }

    s_cur = s_nx;
    d_cur = d_nx;
    __syncthreads();  // h writes visible; swap buffers
    rb ^= 512;
    wb ^= 512;
  }
}

extern "C" void kernel_launch(void* const* d_in, const int* in_sizes, int n_in,
                              void* d_out, int out_size, void* d_ws, size_t ws_size,
                              hipStream_t stream) {
  const float* dur = (const float*)d_in[0];
  const int* sid = (const int*)d_in[1];
  const float* embed = (const float*)d_in[2];
  const float* Wi_f = (const float*)d_in[3];
  const float* Wh_f = (const float*)d_in[4];
  const float* bi_f = (const float*)d_in[5];
  const float* bhn_f = (const float*)d_in[6];
  const float* Wi_b = (const float*)d_in[7];
  const float* Wh_b = (const float*)d_in[8];
  const float* bi_b = (const float*)d_in[9];
  const float* bhn_b = (const float*)d_in[10];
  const float* Wd = (const float*)d_in[11];
  const float* bd = (const float*)d_in[12];
  float* out = (float*)d_out;

  // ws: P4 (2 dirs * 1024 * 256 * 4 f16 = 4 MB) | Bp (768*64 uint4 = 768 KB)
  _Float16* P4 = (_Float16*)d_ws;
  uint4* Bp = (uint4*)((char*)d_ws + (size_t)4 * 1024 * 1024);

  hipMemsetAsync(d_out, 0, (size_t)out_size * sizeof(float), stream);
  hipLaunchKernelGGL(precompute_P, dim3(NSING), dim3(256), 0, stream,
                     embed, Wi_f, bi_f, P4);
  hipLaunchKernelGGL(precompute_P, dim3(NSING), dim3(256), 0, stream,
                     embed, Wi_b, bi_b, P4 + (size_t)NSING * HDIM * 4);
  hipLaunchKernelGGL(pack_B, dim3(768), dim3(64), 0, stream, Wh_f, Wh_b, Bp);
  hipLaunchKernelGGL(gru_scan, dim3(64), dim3(256), 0, stream,
                     dur, sid, Bp, Wi_f, Wi_b, bhn_f, bhn_b, Wd, bd, P4, out);
}